// Round 12
// baseline (4837.849 us; speedup 1.0000x reference)
//
#include <hip/hip_runtime.h>
#include <cstdint>
#include <cstddef>

#define BB 512   // batch
#define TT 512   // seq len
#define HH 100   // hidden
#define G4 400   // 4*H

typedef __attribute__((ext_vector_type(8))) short bf16x8;
typedef __attribute__((ext_vector_type(4))) float f32x4;

// truncation hi/lo bf16 split: x ~= hi + lo with |residual| ~ 2^-17 |x|
static __device__ inline void bsplit(float x, short& h, short& l) {
    const unsigned u = __float_as_uint(x);
    h = (short)(u >> 16);
    const float fh = __uint_as_float(u & 0xffff0000u);
    const float r  = x - fh;
    l = (short)(__float_as_uint(r) >> 16);
}

// ---------------------------------------------------------------------------
// Recurrent kernel: round-6 variant VERBATIM (best measured: 660-700us/layer).
// 448 threads, 1 block/CU; role pairing (i,g)/(f,o) via shfl, one barrier/step;
// weights gathered from LDS staging then clobbered (no remat path).
// ---------------------------------------------------------------------------
template<bool IS_L0, bool WRITE_DROP>
__global__ __launch_bounds__(448, 1)
void rec_kernel(const float* __restrict__ x,       // [B][T] (layer0 input, IN=1)
                const float* __restrict__ xc,      // [T][B][400] (layers>0)
                const float* __restrict__ Whh_l,   // [400][100]
                const float* __restrict__ Wih0,    // [400] (layer0)
                const float* __restrict__ bih_l,   // [400] (layer0)
                const float* __restrict__ bhh_l,   // [400] (layer0)
                const float* __restrict__ dmask_l, // [B][T][100] (if WRITE_DROP)
                float* __restrict__ hdrop,         // [T][B][100] (if WRITE_DROP)
                float* __restrict__ st_h,          // [B][100]
                float* __restrict__ st_c)          // [B][100]
{
    __shared__ float sh[G4 * HH];   // 160,000 B: weight staging, then hbuf

    const int tid  = threadIdx.x;
    const int e    = (tid < 224) ? 0 : 1;
    const int off  = tid - e * 224;            // 0..223
    const int j    = off >> 1;                 // 0..111
    const int role = off & 1;                  // 0: (i,g)  1: (f,o)
    const bool active = (j < HH);
    const int jc   = active ? j : (HH - 1);
    const int r0   = role * 100 + jc;          // i- or f-row (sigmoid)
    const int r1   = r0 + 200;                 // g- or o-row (tanh iff role 0)
    const int b    = blockIdx.x * 2 + e;

    {
        const float4* src = (const float4*)Whh_l;
        float4* dst = (float4*)sh;
        for (int i = tid; i < G4 * HH / 4; i += 448) dst[i] = src[i];
    }
    __syncthreads();

    float4 wf0[25], wf1[25];
    {
        const float4* s0 = (const float4*)&sh[r0 * HH];
        const float4* s1 = (const float4*)&sh[r1 * HH];
        #pragma unroll
        for (int m = 0; m < 25; ++m) { wf0[m] = s0[m]; wf1[m] = s1[m]; }
    }
    __syncthreads();

    for (int i = tid; i < G4 * HH; i += 448) sh[i] = 0.f;

    float wx0 = 0.f, wx1 = 0.f, bs0 = 0.f, bs1 = 0.f;
    if (IS_L0) {
        wx0 = Wih0[r0];  bs0 = bih_l[r0] + bhh_l[r0];
        wx1 = Wih0[r1];  bs1 = bih_l[r1] + bhh_l[r1];
    }

    const bool isB = (role == 1);
    float c2 = 0.f, hlast = 0.f;

    __syncthreads();

    float gin0 = 0.f, gin1 = 0.f, xv = 0.f, mk = 0.f;
    if (IS_L0) {
        xv = x[(size_t)b * TT];
    } else {
        gin0 = xc[(size_t)b * G4 + r0];
        gin1 = xc[(size_t)b * G4 + r1];
    }
    if (WRITE_DROP && isB && active) mk = dmask_l[(size_t)b * TT * HH + jc];

    int cur = 0;
    for (int t = 0; t < TT; ++t) {
        const int tn = (t + 1 < TT) ? (t + 1) : t;

        float nxv = 0.f, ngin0 = 0.f, ngin1 = 0.f, nmk = 0.f;
        if (IS_L0) {
            nxv = x[(size_t)b * TT + tn];
        } else {
            const size_t base = (size_t)tn * (BB * G4) + (size_t)b * G4;
            ngin0 = xc[base + r0];
            ngin1 = xc[base + r1];
        }
        if (WRITE_DROP && isB && active)
            nmk = dmask_l[((size_t)b * TT + tn) * HH + jc];

        if (IS_L0) {
            gin0 = fmaf(xv, wx0, bs0);
            gin1 = fmaf(xv, wx1, bs1);
        }

        float a0 = 0.f, a0b = 0.f, a1 = 0.f, a1b = 0.f;
        {
            const float4* hp = (const float4*)&sh[cur * 224 + e * 112];
            #pragma unroll
            for (int m = 0; m < 25; ++m) {
                const float4 hv = hp[m];
                a0  = fmaf(wf0[m].x, hv.x, a0);
                a0b = fmaf(wf0[m].y, hv.y, a0b);
                a0  = fmaf(wf0[m].z, hv.z, a0);
                a0b = fmaf(wf0[m].w, hv.w, a0b);
                a1  = fmaf(wf1[m].x, hv.x, a1);
                a1b = fmaf(wf1[m].y, hv.y, a1b);
                a1  = fmaf(wf1[m].z, hv.z, a1);
                a1b = fmaf(wf1[m].w, hv.w, a1b);
            }
        }
        const float pre0 = a0 + a0b + gin0;    // i (A) | f (B)
        const float pre1 = a1 + a1b + gin1;    // g (A) | o (B)

        const float s0 = 1.f / (1.f + __expf(-pre0));
        const float E1 = __expf(isB ? (-pre1) : (pre1 + pre1));
        const float rr = 1.f / (1.f + E1);
        const float s1 = isB ? rr : fmaf(-2.f, rr, 1.f);

        const float pv   = s0 * s1;
        const float recv = __shfl_xor(pv, 1);

        const int nxt = cur ^ 1;
        if (isB) {
            c2 = fmaf(s0, c2, recv);                      // c = f*c + i*g
            const float Ec = __expf(c2 + c2);
            const float th = 1.f - 2.f / (Ec + 1.f);      // tanh(c)
            const float h  = s1 * th;                     // o * tanh(c)
            hlast = h;
            if (active) {
                sh[nxt * 224 + e * 112 + j] = h;
                if (WRITE_DROP)
                    hdrop[((size_t)t * BB + b) * HH + j] = h * mk * 2.f;
            }
        }
        __syncthreads();
        cur = nxt;
        gin0 = ngin0; gin1 = ngin1; xv = nxv; mk = nmk;
    }

    if (isB && active) {
        st_h[(size_t)b * HH + j] = hlast;
        st_c[(size_t)b * HH + j] = c2;
    }
}

// ---------------------------------------------------------------------------
// W-split prep: WihR[3][400][100] fp32 -> whi/wlo[3][448][128] bf16 (short),
// zero-padded in n (400->448) and k (100->128). Fragment-friendly row-major.
// ---------------------------------------------------------------------------
__global__ __launch_bounds__(256)
void wprep(const float* __restrict__ WihR, short* __restrict__ whi,
           short* __restrict__ wlo)
{
    const int idx = blockIdx.x * 256 + threadIdx.x;
    if (idx >= 3 * 448 * 128) return;
    const int k = idx & 127;
    const int n = (idx >> 7) % 448;
    const int l = idx / (448 * 128);
    short h = 0, lo = 0;
    if (n < G4 && k < HH)
        bsplit(WihR[(size_t)l * G4 * HH + (size_t)n * HH + k], h, lo);
    whi[idx] = h;
    wlo[idx] = lo;
}

// ---------------------------------------------------------------------------
// MFMA GEMM: xc[m][n] = sum_k A[m][k]*W[n][k] + bias[n].
// A split to bf16 hi/lo in LDS; W pre-split in ws. 4 cross-product MFMAs
// (hh+hl+lh+ll) accumulate in fp32 -> error ~2^-17, far under threshold.
// Block 128M x 64N, 256 thr (4 waves x 32M); K padded 100->128 (4 chunks).
// LDS [128][136] shorts: rows 272B -> 16B-aligned b128 reads, <=2-way banks.
// ---------------------------------------------------------------------------
__global__ __launch_bounds__(256, 2)
void xc_gemm_mfma(const float* __restrict__ A,    // [M][100]
                  const short* __restrict__ whi,  // [448][128]
                  const short* __restrict__ wlo,  // [448][128]
                  const float* __restrict__ bih_l,
                  const float* __restrict__ bhh_l,
                  float* __restrict__ xc)         // [M][400]
{
    __shared__ short Ah[128][136];
    __shared__ short Al[128][136];

    const int tid = threadIdx.x;
    const int nb  = blockIdx.x;                 // 0..6
    const size_t m0 = (size_t)blockIdx.y * 128;

    for (int idx = tid; idx < 128 * 128; idx += 256) {
        const int r = idx >> 7, k = idx & 127;
        short h = 0, l = 0;
        if (k < HH) bsplit(A[(m0 + r) * HH + k], h, l);
        Ah[r][k] = h;
        Al[r][k] = l;
    }
    __syncthreads();

    const int w  = tid >> 6;        // wave 0..3 -> M rows [32w, 32w+32)
    const int ln = tid & 63;
    const int lr = ln & 15;
    const int lk = (ln >> 4) * 8;   // k sub-base within 32-chunk

    f32x4 acc[2][4] = {};

    #pragma unroll
    for (int kc = 0; kc < 4; ++kc) {
        const int kb = kc * 32 + lk;
        bf16x8 ah[2], al[2], bh[4], bl[4];
        #pragma unroll
        for (int mt = 0; mt < 2; ++mt) {
            const int row = w * 32 + mt * 16 + lr;
            ah[mt] = *(const bf16x8*)&Ah[row][kb];
            al[mt] = *(const bf16x8*)&Al[row][kb];
        }
        #pragma unroll
        for (int nt = 0; nt < 4; ++nt) {
            const size_t col = (size_t)nb * 64 + nt * 16 + lr;
            bh[nt] = *(const bf16x8*)&whi[col * 128 + kb];
            bl[nt] = *(const bf16x8*)&wlo[col * 128 + kb];
        }
        #pragma unroll
        for (int mt = 0; mt < 2; ++mt)
            #pragma unroll
            for (int nt = 0; nt < 4; ++nt) {
                acc[mt][nt] = __builtin_amdgcn_mfma_f32_16x16x32_bf16(
                    ah[mt], bh[nt], acc[mt][nt], 0, 0, 0);
                acc[mt][nt] = __builtin_amdgcn_mfma_f32_16x16x32_bf16(
                    ah[mt], bl[nt], acc[mt][nt], 0, 0, 0);
                acc[mt][nt] = __builtin_amdgcn_mfma_f32_16x16x32_bf16(
                    al[mt], bh[nt], acc[mt][nt], 0, 0, 0);
                acc[mt][nt] = __builtin_amdgcn_mfma_f32_16x16x32_bf16(
                    al[mt], bl[nt], acc[mt][nt], 0, 0, 0);
            }
    }

    // epilogue: C[row=(ln>>4)*4+r][col=ln&15] per tile (verified C/D layout)
    #pragma unroll
    for (int nt = 0; nt < 4; ++nt) {
        const int col = nb * 64 + nt * 16 + lr;
        if (col < G4) {
            const float bias = bih_l[col] + bhh_l[col];
            #pragma unroll
            for (int mt = 0; mt < 2; ++mt) {
                const size_t rowb = m0 + w * 32 + mt * 16 + (ln >> 4) * 4;
                #pragma unroll
                for (int r = 0; r < 4; ++r)
                    xc[(rowb + r) * G4 + col] = acc[mt][nt][r] + bias;
            }
        }
    }
}

// ---------------------------------------------------------------------------
__global__ __launch_bounds__(256)
void out_kernel(const float* __restrict__ st_h3,  // [B][100]
                const float* __restrict__ Wout,   // [100]
                const float* __restrict__ bout,   // [1]
                float* __restrict__ out)          // [B]
{
    const int b = blockIdx.x * 256 + threadIdx.x;
    if (b < BB) {
        float sum = bout[0];
        #pragma unroll 4
        for (int k = 0; k < HH; ++k)
            sum = fmaf(st_h3[(size_t)b * HH + k], Wout[k], sum);
        out[b] = sum;
    }
}

// ---------------------------------------------------------------------------
extern "C" void kernel_launch(void* const* d_in, const int* in_sizes, int n_in,
                              void* d_out, int out_size, void* d_ws, size_t ws_size,
                              hipStream_t stream)
{
    const float* x     = (const float*)d_in[0];  // [512][512][1]
    const float* Wih0  = (const float*)d_in[1];  // [400][1]
    const float* WihR  = (const float*)d_in[2];  // [3][400][100]
    const float* Whh   = (const float*)d_in[3];  // [4][400][100]
    const float* bih   = (const float*)d_in[4];  // [4][400]
    const float* bhh   = (const float*)d_in[5];  // [4][400]
    const float* Wout  = (const float*)d_in[6];  // [1][100]
    const float* bout  = (const float*)d_in[7];  // [1]
    const float* dmask = (const float*)d_in[8];  // [3][512][512][100]
    float* out = (float*)d_out;

    // ws layout (floats): ~527 MB of the 1200 MB workspace
    float* ws    = (float*)d_ws;
    float* xcb   = ws;                                  // T*B*400 = 104,857,600
    float* hdrop = xcb + (size_t)TT * BB * G4;          // T*B*100 =  26,214,400
    float* sth   = hdrop + (size_t)TT * BB * HH;        // 4*B*100
    float* stc   = sth + (size_t)4 * BB * HH;           // 4*B*100
    short* whi   = (short*)(stc + (size_t)4 * BB * HH); // 3*448*128 shorts
    short* wlo   = whi + (size_t)3 * 448 * 128;

    const dim3 rgrid(BB / 2), rblk(448);
    const dim3 ggrid(7, (TT * BB) / 128), gblk(256);

    wprep<<<dim3((3 * 448 * 128 + 255) / 256), dim3(256), 0, stream>>>(WihR, whi, wlo);

    // layer 0 (input dim 1 fused into rec)
    rec_kernel<true, true><<<rgrid, rblk, 0, stream>>>(
        x, nullptr, Whh, Wih0, bih, bhh, dmask,
        hdrop, sth, stc);
    // layers 1..3
    for (int l = 1; l < 4; ++l) {
        xc_gemm_mfma<<<ggrid, gblk, 0, stream>>>(
            hdrop, whi + (size_t)(l - 1) * 448 * 128,
            wlo + (size_t)(l - 1) * 448 * 128,
            bih + l * G4, bhh + l * G4, xcb);
        if (l < 3) {
            rec_kernel<false, true><<<rgrid, rblk, 0, stream>>>(
                nullptr, xcb, Whh + (size_t)l * G4 * HH,
                nullptr, nullptr, nullptr,
                dmask + (size_t)l * BB * TT * HH,
                hdrop, sth + (size_t)l * BB * HH, stc + (size_t)l * BB * HH);
        } else {
            rec_kernel<false, false><<<rgrid, rblk, 0, stream>>>(
                nullptr, xcb, Whh + (size_t)l * G4 * HH,
                nullptr, nullptr, nullptr,
                nullptr,
                nullptr, sth + (size_t)l * BB * HH, stc + (size_t)l * BB * HH);
        }
    }
    out_kernel<<<dim3(2), dim3(256), 0, stream>>>(sth + (size_t)3 * BB * HH, Wout, bout, out);
}